// Round 1
// 311.547 us; speedup vs baseline: 1.1221x; 1.1221x over previous
//
#include <hip/hip_runtime.h>

#define NMAT 2048

typedef float f32x4 __attribute__((ext_vector_type(4)));

__device__ __forceinline__ float4 f4fma(float a, float4 b, float4 c) {
    return make_float4(fmaf(a, b.x, c.x), fmaf(a, b.y, c.y),
                       fmaf(a, b.z, c.z), fmaf(a, b.w, c.w));
}
__device__ __forceinline__ float4 f4scale(float a, float4 b) {
    return make_float4(a * b.x, a * b.y, a * b.z, a * b.w);
}

// One pass over `in`: rowsum, colsum, diag, trace, totsum.
// 256 blocks x 256 threads; block b owns rows 8b..8b+7, all 2048 cols.
// Each thread owns 8 exclusive columns (4t..4t+3, 1024+4t..+3) -> register
// colsum partials, one atomicAdd per column per block (256-way contention).
__global__ __launch_bounds__(256) void k_stats(const float* __restrict__ in,
                                               float* __restrict__ rowsum,
                                               float* __restrict__ diag,
                                               float* __restrict__ colsum,
                                               float* __restrict__ scal) {
    const int t = threadIdx.x;
    const int r0 = blockIdx.x * 8;
    __shared__ float lrs[8][256];
    float4 c0 = make_float4(0.f, 0.f, 0.f, 0.f);
    float4 c1 = make_float4(0.f, 0.f, 0.f, 0.f);
#pragma unroll
    for (int r = 0; r < 8; ++r) {
        const float4* row = (const float4*)(in + (size_t)(r0 + r) * NMAT);
        float4 v0 = row[t];
        float4 v1 = row[t + 256];
        c0.x += v0.x; c0.y += v0.y; c0.z += v0.z; c0.w += v0.w;
        c1.x += v1.x; c1.y += v1.y; c1.z += v1.z; c1.w += v1.w;
        lrs[r][t] = ((v0.x + v0.y) + (v0.z + v0.w)) +
                    ((v1.x + v1.y) + (v1.z + v1.w));
    }
    // colsum partials: thread-exclusive columns within the block.
    atomicAdd(&colsum[4 * t + 0], c0.x);
    atomicAdd(&colsum[4 * t + 1], c0.y);
    atomicAdd(&colsum[4 * t + 2], c0.z);
    atomicAdd(&colsum[4 * t + 3], c0.w);
    atomicAdd(&colsum[1024 + 4 * t + 0], c1.x);
    atomicAdd(&colsum[1024 + 4 * t + 1], c1.y);
    atomicAdd(&colsum[1024 + 4 * t + 2], c1.z);
    atomicAdd(&colsum[1024 + 4 * t + 3], c1.w);
    __syncthreads();
    // rowsum: 32 lanes per row; lanes l and l+32 hit distinct rows but the
    // same bank -> 2-way aliasing, which is free on CDNA4.
    {
        const int row = t >> 5;
        const int lane = t & 31;
        float s = 0.f;
#pragma unroll
        for (int k = 0; k < 8; ++k) s += lrs[row][lane + 32 * k];
        s += __shfl_down(s, 16);
        s += __shfl_down(s, 8);
        s += __shfl_down(s, 4);
        s += __shfl_down(s, 2);
        s += __shfl_down(s, 1);
        if (lane == 0) {
            rowsum[r0 + row] = s;
            atomicAdd(&scal[1], s);   // totsum
        }
    }
    if (t < 8) {
        const int r = r0 + t;
        const float d = in[(size_t)r * NMAT + r];
        diag[r] = d;
        atomicAdd(&scal[0], d);       // trace
    }
}

// Main: 32x32 (i,j) tile per block, 256 threads. Lane owns fixed (tj, og);
// loops i over the tile. P/Q/D recomputed from the per-row stats (cheap VALU,
// kernel is store-BW-bound). Non-temporal float4 stores: output is
// write-once, keep it out of L2 so `in` stays resident for transposed reads.
__global__ __launch_bounds__(256) void k_main(const float* __restrict__ in,
                                              const float* __restrict__ w,
                                              const float* __restrict__ rowsum,
                                              const float* __restrict__ diag,
                                              const float* __restrict__ colsum,
                                              const float* __restrict__ scal,
                                              float4* __restrict__ out4) {
    const int t = threadIdx.x;
    const int og = t & 3;
    const int tj = (t >> 2) & 31;
    const int half = t >> 7;                 // 0/1 -> even/odd i within tile
    const int j = blockIdx.x * 32 + tj;
    const int i0 = blockIdx.y * 32;
    const bool dblk = (blockIdx.x == blockIdx.y);
    const float4* W = (const float4*)w;      // W[k*4+og] = w[k][og*4 .. og*4+3]
    const float4 w8 = W[8 * 4 + og], w9 = W[9 * 4 + og], w10 = W[10 * 4 + og];
    const float4 w11 = W[11 * 4 + og], w12 = W[12 * 4 + og];
    const float tr = scal[0], ts = scal[1];
    // j-invariant base: Q(j) + ones-terms (trace*w13 + totsum*w14).
    float4 base = f4scale(diag[j], W[5 * 4 + og]);
    base = f4fma(rowsum[j], W[6 * 4 + og], base);
    base = f4fma(colsum[j], W[7 * 4 + og], base);
    base = f4fma(tr, W[13 * 4 + og], base);
    base = f4fma(ts, W[14 * 4 + og], base);
    const size_t jrow = (size_t)j * NMAT;
#pragma unroll 8
    for (int it = 0; it < 16; ++it) {
        const int i = i0 + half + 2 * it;
        const float di = diag[i];
        const float rsi = rowsum[i];
        const float csi = colsum[i];
        const float a = in[(size_t)i * NMAT + j];   // direct element
        const float at = in[jrow + i];              // transposed element
        float4 r = f4fma(di, w8, base);
        r = f4fma(rsi, w9, r);
        r = f4fma(csi, w10, r);
        r = f4fma(a, w12, r);
        r = f4fma(at, w11, r);
        if (dblk && i == j) {
            float4 dd = f4scale(di, W[0 * 4 + og]);
            dd = f4fma(rsi, W[1 * 4 + og], dd);
            dd = f4fma(csi, W[2 * 4 + og], dd);
            dd = f4fma(tr, W[3 * 4 + og], dd);
            dd = f4fma(ts, W[4 * 4 + og], dd);
            r.x += dd.x; r.y += dd.y; r.z += dd.z; r.w += dd.w;
        }
        f32x4 rv = {r.x, r.y, r.z, r.w};
        __builtin_nontemporal_store(
            rv, (f32x4*)&out4[((size_t)i * NMAT + j) * 4 + og]);
    }
}

extern "C" void kernel_launch(void* const* d_in, const int* in_sizes, int n_in,
                              void* d_out, int out_size, void* d_ws, size_t ws_size,
                              hipStream_t stream) {
    const float* in = (const float*)d_in[0];   // [2048, 2048] f32
    const float* w = (const float*)d_in[1];    // [15, 16] f32
    float* ws = (float*)d_ws;

    // Workspace layout (floats):
    //   [0,2048)      colsum   (atomic-accumulated; zeroed below)
    //   [2048,2050)   scal: trace, totsum (atomic; zeroed below)
    //   [2056,4104)   rowsum
    //   [4104,6152)   diag
    float* colsum = ws;
    float* scal = ws + 2048;
    float* rowsum = ws + 2056;
    float* diag = ws + 4104;

    hipMemsetAsync(d_ws, 0, 2050 * sizeof(float), stream);
    k_stats<<<256, 256, 0, stream>>>(in, rowsum, diag, colsum, scal);
    k_main<<<dim3(64, 64), 256, 0, stream>>>(in, w, rowsum, diag, colsum, scal,
                                             (float4*)d_out);
}